// Round 9
// baseline (4778.653 us; speedup 1.0000x reference)
//
#include <hip/hip_runtime.h>
#include <hip/hip_bf16.h>

// ---------------- problem constants ----------------
#define BSZ 2
#define LSEQ 2048
#define DIM 1024
#define VOCAB 32000
#define NLAYER 4
#define DSTATE 128
#define DCONV 4
#define HEADDIM 64
#define DIN 2048
#define NH 32
#define CONVDIM 2304          // DIN + 2*DSTATE
#define DPROJ 4384            // 2*DIN + 2*DSTATE + NH
#define FFN 4096
#define QLEN 128
#define NTOK 4096             // BSZ*LSEQ
#define NCHUNK 32             // NTOK/QLEN
#define CPB 16                // chunks per batch

#define SMEM2 131072          // 2 x (A 32KB + B 32KB)

using f32x4 = __attribute__((ext_vector_type(4))) float;
using f16   = _Float16;
using f16x4 = __attribute__((ext_vector_type(4))) _Float16;
using f16x8 = __attribute__((ext_vector_type(8))) _Float16;

__device__ __forceinline__ void gld16(const void* g, void* l) {
  __builtin_amdgcn_global_load_lds(
      (const __attribute__((address_space(1))) unsigned int*)g,
      (__attribute__((address_space(3))) unsigned int*)l, 16, 0, 0);
}

// Tile swizzle: XCD-contiguous + column-chunked (8 bx per chunk, sweep all by)
__device__ __forceinline__ void swz_tiles(int& bx, int& by) {
  const int nx = gridDim.x, ny = gridDim.y;
  const int nwg = nx * ny;
  int bid = blockIdx.y * nx + blockIdx.x;
  if ((nwg & 7) == 0) bid = (bid & 7) * (nwg >> 3) + (bid >> 3);
  const int CW = 8;
  const int nchx = nx / CW;
  const int per = CW * ny;
  const int ch = bid / per;
  if (ch < nchx) {
    int wi = bid - ch * per;
    bx = ch * CW + (wi & (CW - 1));
    by = wi / CW;
  } else {
    int tb = bid - nchx * per;
    int tw = nx - nchx * CW;
    bx = nchx * CW + (tb % tw);
    by = tb / tw;
  }
}

// ---------------- pipelined fp16 GEMM: 256x256 tile, BK=64, 2-buffer counted-vmcnt ----------------
// C(f32) = A * B^T (+bias). Split-K via blockIdx.z (Cf advanced z*M*ldc; bias null then).
// 8 waves as 2(row)x4(col); wave tile 128x64 -> 8 A-frags + 4 B-frags per 32 MFMAs
// (42.7 FLOP per LDS byte; LDS read time < matrix time per tile).
// Ledger: 8 gld16/thread/stage; in-loop stage(t+1) then vmcnt(8) retires tile t's
// loads exactly. Tail vmcnt(0). No other vmem in loop. XOR swizzle slot=g^(row&7)
// via pre-swizzled global source (linear gload_lds dest) + swizzled ds_read.
__global__ __launch_bounds__(512, 2) void gemm_p2(
    const f16* __restrict__ A, const f16* __restrict__ B,
    float* __restrict__ Cf, const float* __restrict__ bias,
    int N, int Ksub, int lda, int ldb, int ldc)
{
  extern __shared__ char smem[];
  const int tid  = threadIdx.x;
  const int lane = tid & 63;
  const int wid  = tid >> 6;
  int bx, by; swz_tiles(bx, by);
  const int m0 = by * 256;
  const int n0 = bx * 256;
  const size_t kbase = (size_t)blockIdx.z * Ksub;
  if (gridDim.z > 1) Cf += (size_t)blockIdx.z * (size_t)gridDim.y * 256 * ldc;
  const int NT = Ksub >> 6;

  int arA[4], acA[4], brB[4], bcB[4];
#pragma unroll
  for (int L = 0; L < 4; ++L) {
    int q = L * 512 + tid;
    int row = q >> 3;
    arA[L] = m0 + row;
    acA[L] = ((q & 7) ^ (row & 7)) << 3;
    int r = n0 + row; if (r > N - 1) r = N - 1;
    brB[L] = r;
    bcB[L] = acA[L];
  }

  auto stage = [&](int tt) {
    const int b = tt & 1;
    char* Ad = smem + b * 65536;
    char* Bd = Ad + 32768;
    const int kb = tt << 6;
#pragma unroll
    for (int L = 0; L < 4; ++L)
      gld16(A + (size_t)arA[L] * lda + kbase + kb + acA[L], Ad + (L * 512 + tid) * 16);
#pragma unroll
    for (int L = 0; L < 4; ++L)
      gld16(B + (size_t)brB[L] * ldb + kbase + kb + bcB[L], Bd + (L * 512 + tid) * 16);
  };

  const int wm = (wid >> 2) << 7;   // 0,128
  const int wn = (wid & 3) << 6;    // 0,64,128,192
  const int fr = lane & 15;
  const int kg = lane >> 4;

  f32x4 acc[4][8] = {};             // [i col-frag][j row-frag]

  stage(0);

  for (int t = 0; t < NT; ++t) {
    if (t + 1 < NT) {
      stage(t + 1);
      asm volatile("s_waitcnt vmcnt(8)" ::: "memory");
    } else {
      asm volatile("s_waitcnt vmcnt(0)" ::: "memory");
    }
    __builtin_amdgcn_s_barrier();
    asm volatile("" ::: "memory");
    const f16* Ab = (const f16*)(smem + (t & 1) * 65536);
    const f16* Bb = Ab + 16384;     // +32768 bytes
#pragma unroll
    for (int s = 0; s < 2; ++s) {
      const int g = kg + s * 4;
      f16x8 af[8], bf[4];
#pragma unroll
      for (int j = 0; j < 8; ++j) {
        int row = wm + j * 16 + fr;
        af[j] = *(const f16x8*)&Ab[row * 64 + ((g ^ (row & 7)) << 3)];
      }
#pragma unroll
      for (int i = 0; i < 4; ++i) {
        int row = wn + i * 16 + fr;
        bf[i] = *(const f16x8*)&Bb[row * 64 + ((g ^ (row & 7)) << 3)];
      }
#pragma unroll
      for (int i = 0; i < 4; ++i)
#pragma unroll
        for (int j = 0; j < 8; ++j)
          acc[i][j] = __builtin_amdgcn_mfma_f32_16x16x32_f16(bf[i], af[j], acc[i][j], 0, 0, 0);
    }
    asm volatile("" ::: "memory");
    __builtin_amdgcn_s_barrier();
    asm volatile("" ::: "memory");
  }

  const int c4 = kg << 2;
#pragma unroll
  for (int i = 0; i < 4; ++i) {
    const int col = n0 + wn + i * 16 + c4;
    if (col >= N) continue;          // N%16==0 -> uniform per frag
    f32x4 bv = bias ? *(const f32x4*)(bias + col) : f32x4{0, 0, 0, 0};
#pragma unroll
    for (int j = 0; j < 8; ++j) {
      const int row = m0 + wm + j * 16 + fr;
      *(f32x4*)(Cf + (size_t)row * ldc + col) = acc[i][j] + bv;
    }
  }
}

// ---------------- pipelined UV GEMM: G(f16) = (A Bu^T) .* (A Bv^T), 256x128 tile ----------------
// B-stage = [Bu rows n0..n0+127 ; Bv rows n0..n0+127] (256x64). A-frags reused for both
// products -> 12 frag-reads per 32 MFMAs. Same 2-buffer vmcnt(8) ledger as gemm_p2.
__global__ __launch_bounds__(512, 2) void gemm_uv2(
    const f16* __restrict__ A, const f16* __restrict__ Bu, const f16* __restrict__ Bv,
    f16* __restrict__ Gh)
{
  extern __shared__ char smem[];
  const int tid  = threadIdx.x;
  const int lane = tid & 63;
  const int wid  = tid >> 6;
  int bx, by; swz_tiles(bx, by);
  const int m0 = by * 256;
  const int n0 = bx * 128;
  const int NT = DIM >> 6;

  int arA[4], acA[4];
  const f16* bp[4];
  int bcB[4];
#pragma unroll
  for (int L = 0; L < 4; ++L) {
    int q = L * 512 + tid;
    int row = q >> 3;
    arA[L] = m0 + row;
    acA[L] = ((q & 7) ^ (row & 7)) << 3;
    bcB[L] = acA[L];
    bp[L] = (row < 128) ? (Bu + (size_t)(n0 + row) * DIM)
                        : (Bv + (size_t)(n0 + row - 128) * DIM);
  }

  auto stage = [&](int tt) {
    const int b = tt & 1;
    char* Ad = smem + b * 65536;
    char* Bd = Ad + 32768;
    const int kb = tt << 6;
#pragma unroll
    for (int L = 0; L < 4; ++L)
      gld16(A + (size_t)arA[L] * DIM + kb + acA[L], Ad + (L * 512 + tid) * 16);
#pragma unroll
    for (int L = 0; L < 4; ++L)
      gld16(bp[L] + kb + bcB[L], Bd + (L * 512 + tid) * 16);
  };

  const int wm = (wid >> 1) << 6;   // 0,64,128,192
  const int wn = (wid & 1) << 6;    // 0,64
  const int fr = lane & 15;
  const int kg = lane >> 4;

  f32x4 accu[4][4] = {}, accv[4][4] = {};

  stage(0);

  for (int t = 0; t < NT; ++t) {
    if (t + 1 < NT) {
      stage(t + 1);
      asm volatile("s_waitcnt vmcnt(8)" ::: "memory");
    } else {
      asm volatile("s_waitcnt vmcnt(0)" ::: "memory");
    }
    __builtin_amdgcn_s_barrier();
    asm volatile("" ::: "memory");
    const f16* Ab = (const f16*)(smem + (t & 1) * 65536);
    const f16* Bb = Ab + 16384;
#pragma unroll
    for (int s = 0; s < 2; ++s) {
      const int g = kg + s * 4;
      f16x8 af[4], bfu[4], bfv[4];
#pragma unroll
      for (int j = 0; j < 4; ++j) {
        int row = wm + j * 16 + fr;
        af[j] = *(const f16x8*)&Ab[row * 64 + ((g ^ (row & 7)) << 3)];
      }
#pragma unroll
      for (int i = 0; i < 4; ++i) {
        int ru = wn + i * 16 + fr;
        int rv = 128 + wn + i * 16 + fr;
        bfu[i] = *(const f16x8*)&Bb[ru * 64 + ((g ^ (ru & 7)) << 3)];
        bfv[i] = *(const f16x8*)&Bb[rv * 64 + ((g ^ (rv & 7)) << 3)];
      }
#pragma unroll
      for (int i = 0; i < 4; ++i)
#pragma unroll
        for (int j = 0; j < 4; ++j) {
          accu[i][j] = __builtin_amdgcn_mfma_f32_16x16x32_f16(bfu[i], af[j], accu[i][j], 0, 0, 0);
          accv[i][j] = __builtin_amdgcn_mfma_f32_16x16x32_f16(bfv[i], af[j], accv[i][j], 0, 0, 0);
        }
    }
    asm volatile("" ::: "memory");
    __builtin_amdgcn_s_barrier();
    asm volatile("" ::: "memory");
  }

  const int c4 = kg << 2;
#pragma unroll
  for (int i = 0; i < 4; ++i) {
    const int col = n0 + wn + i * 16 + c4;
#pragma unroll
    for (int j = 0; j < 4; ++j) {
      const int row = m0 + wm + j * 16 + fr;
      f16x4 h;
#pragma unroll
      for (int r = 0; r < 4; ++r)
        h[r] = (f16)(accu[i][j][r] * accv[i][j][r]);
      *(f16x4*)(Gh + (size_t)row * FFN + col) = h;
    }
  }
}

// deterministic split-K reduce: out = resid + sum_p parts[p]
__global__ __launch_bounds__(256) void reduce_k(const float* __restrict__ parts,
                                                const float* __restrict__ resid,
                                                float* __restrict__ out,
                                                int np, int n)
{
  const size_t i = ((size_t)blockIdx.x * 256 + threadIdx.x) * 4;
  if (i >= (size_t)n) return;
  f32x4 s = *(const f32x4*)(resid + i);
  for (int p = 0; p < np; ++p)
    s += *(const f32x4*)(parts + (size_t)p * n + i);
  *(f32x4*)(out + i) = s;
}

// ---------------- small kernels ----------------
__global__ __launch_bounds__(256) void cvt_f2h_k(const float* __restrict__ src,
                                                 f16* __restrict__ dst, int n)
{
  for (size_t i = ((size_t)blockIdx.x * 256 + threadIdx.x) * 4; i < (size_t)n;
       i += (size_t)gridDim.x * 1024) {
    f32x4 v = *(const f32x4*)(src + i);
    f16x4 o;
#pragma unroll
    for (int c = 0; c < 4; ++c) o[c] = (f16)v[c];
    *(f16x4*)(dst + i) = o;
  }
}

__global__ __launch_bounds__(256) void gather_k(const int* __restrict__ tok,
                                                const float* __restrict__ emb,
                                                float* __restrict__ x)
{
  const int row = blockIdx.x;
  const int t = tok[row];
  const f32x4* s = (const f32x4*)(emb + (size_t)t * DIM);
  f32x4* d = (f32x4*)(x + (size_t)row * DIM);
  d[threadIdx.x] = s[threadIdx.x];
}

// rms over 1024; writes f32 and fp16 copies
__global__ __launch_bounds__(256) void rms1024(const float* __restrict__ in,
                                               float* __restrict__ outf,
                                               f16* __restrict__ outh)
{
  const int row = blockIdx.x, tid = threadIdx.x;
  f32x4 v = ((const f32x4*)(in + (size_t)row * DIM))[tid];
  float ss = v[0] * v[0] + v[1] * v[1] + v[2] * v[2] + v[3] * v[3];
  for (int o = 32; o; o >>= 1) ss += __shfl_down(ss, o);
  __shared__ float red[4];
  if ((tid & 63) == 0) red[tid >> 6] = ss;
  __syncthreads();
  ss = red[0] + red[1] + red[2] + red[3];
  const float sc = rsqrtf(ss * (1.f / 1024.f) + 1e-6f);
  f32x4 o4 = v * sc;
  ((f32x4*)(outf + (size_t)row * DIM))[tid] = o4;
  f16x4 h;
#pragma unroll
  for (int c = 0; c < 4; ++c) h[c] = (f16)o4[c];
  ((f16x4*)(outh + (size_t)row * DIM))[tid] = h;
}

// causal depthwise conv (width 4) + bias + silu; sliding-window registers.
__global__ __launch_bounds__(256) void conv_silu2(const float* __restrict__ zx,
                                                  const float* __restrict__ cw,
                                                  const float* __restrict__ cbias,
                                                  float* __restrict__ xbc)
{
  const int sid = blockIdx.x * 256 + threadIdx.x;
  const int c0 = (sid % 576) * 4;
  const int t0 = (sid / 576) * 16;
  float w[4][4], bs[4];
#pragma unroll
  for (int cc = 0; cc < 4; ++cc) {
    f32x4 wv = *(const f32x4*)(cw + (size_t)(c0 + cc) * 4);
    w[cc][0] = wv[0]; w[cc][1] = wv[1]; w[cc][2] = wv[2]; w[cc][3] = wv[3];
    bs[cc] = cbias[c0 + cc];
  }
  const int l0 = t0 & (LSEQ - 1);
  f32x4 x3 = {0, 0, 0, 0}, x2 = {0, 0, 0, 0}, x1 = {0, 0, 0, 0};
  if (l0 != 0) {
    x3 = *(const f32x4*)(zx + (size_t)(t0 - 3) * DPROJ + DIN + c0);
    x2 = *(const f32x4*)(zx + (size_t)(t0 - 2) * DPROJ + DIN + c0);
    x1 = *(const f32x4*)(zx + (size_t)(t0 - 1) * DPROJ + DIN + c0);
  }
  for (int i = 0; i < 16; ++i) {
    const int t = t0 + i;
    f32x4 xc = *(const f32x4*)(zx + (size_t)t * DPROJ + DIN + c0);
    f32x4 o;
#pragma unroll
    for (int cc = 0; cc < 4; ++cc) {
      float a = bs[cc] + x3[cc] * w[cc][0] + x2[cc] * w[cc][1] +
                x1[cc] * w[cc][2] + xc[cc] * w[cc][3];
      o[cc] = a / (1.f + expf(-a));
    }
    *(f32x4*)(xbc + (size_t)t * CONVDIM + c0) = o;
    x3 = x2; x2 = x1; x1 = xc;
  }
}

// dt = softplus(dtraw + bias); a = dt * (-exp(A_log)); ca = cumsum within chunk
__global__ __launch_bounds__(128) void dt_ca(const float* __restrict__ zx,
                                             const float* __restrict__ dtb,
                                             const float* __restrict__ alog,
                                             float* __restrict__ dt,
                                             float* __restrict__ ca)
{
  const int bc = blockIdx.x >> 5, h = blockIdx.x & 31, q = threadIdx.x;
  const int t = bc * 128 + q;
  float raw = zx[(size_t)t * DPROJ + (DIN + CONVDIM) + h] + dtb[h];
  float d = raw > 20.f ? raw : log1pf(expf(raw));
  dt[t * 32 + h] = d;
  float a = -expf(alog[h]) * d;
  __shared__ float s[128];
  s[q] = a;
  __syncthreads();
  for (int off = 1; off < 128; off <<= 1) {
    float v = (q >= off) ? s[q - off] : 0.f;
    __syncthreads();
    s[q] += v;
    __syncthreads();
  }
  ca[(size_t)blockIdx.x * 128 + q] = s[q];
}

// CB[bc][i][j] = sum_n C[i,n]*B[j,n]
__global__ __launch_bounds__(256) void cb_kernel(const float* __restrict__ xbc,
                                                 float* __restrict__ CB)
{
  const int bc = blockIdx.x;
  __shared__ float Bs[128][32], Cs[128][32];
  float acc[8][8] = {};
  const int ti = threadIdx.x >> 4, tj = threadIdx.x & 15;
  for (int n0 = 0; n0 < 128; n0 += 32) {
    __syncthreads();
    for (int e = threadIdx.x; e < 4096; e += 256) {
      int r = e >> 5, c = e & 31;
      const float* row = xbc + (size_t)(bc * 128 + r) * CONVDIM + DIN;
      Bs[r][c] = row[n0 + c];
      Cs[r][c] = row[DSTATE + n0 + c];
    }
    __syncthreads();
    for (int n = 0; n < 32; ++n) {
      float cv[8], bv[8];
#pragma unroll
      for (int ii = 0; ii < 8; ++ii) cv[ii] = Cs[ti * 8 + ii][n];
#pragma unroll
      for (int jj = 0; jj < 8; ++jj) bv[jj] = Bs[tj * 8 + jj][n];
#pragma unroll
      for (int ii = 0; ii < 8; ++ii)
#pragma unroll
        for (int jj = 0; jj < 8; ++jj) acc[ii][jj] += cv[ii] * bv[jj];
    }
  }
  for (int ii = 0; ii < 8; ++ii)
    for (int jj = 0; jj < 8; ++jj)
      CB[(size_t)bc * 16384 + (size_t)(ti * 8 + ii) * 128 + (tj * 8 + jj)] = acc[ii][jj];
}

// states[n][p] = sum_j exp(ca_last-ca_j)*dt_j*B[j][n]*x[j][p]   (layout [bc][h][n][p])
__global__ __launch_bounds__(256) void states_k(const float* __restrict__ xbc,
                                                const float* __restrict__ dt,
                                                const float* __restrict__ ca,
                                                float* __restrict__ states)
{
  const int bc = blockIdx.x >> 5, h = blockIdx.x & 31;
  __shared__ float xw[128][64];
  __shared__ float Bs[32][128];
  __shared__ float warr[128];
  const int tid = threadIdx.x;
  if (tid < 128) {
    float cv = ca[(size_t)blockIdx.x * 128 + tid];
    float clast = ca[(size_t)blockIdx.x * 128 + 127];
    warr[tid] = expf(clast - cv) * dt[(size_t)(bc * 128 + tid) * 32 + h];
  }
  __syncthreads();
  for (int e = tid * 4; e < 8192; e += 1024) {
    int j = e >> 6, p = e & 63;
    f32x4 xv = *(const f32x4*)(xbc + (size_t)(bc * 128 + j) * CONVDIM + h * 64 + p);
    *(f32x4*)&xw[j][p] = xv * warr[j];
  }
  const int w = tid >> 6, p = tid & 63;
  f32x4 acc[8] = {};
  for (int jc = 0; jc < 128; jc += 32) {
    __syncthreads();
    for (int e = tid * 4; e < 4096; e += 1024) {
      int j = e >> 7, n = e & 127;
      *(f32x4*)&Bs[j][n] =
          *(const f32x4*)(xbc + (size_t)(bc * 128 + jc + j) * CONVDIM + DIN + n);
    }
    __syncthreads();
    for (int j = 0; j < 32; ++j) {
      float xv = xw[jc + j][p];
      const f32x4* br = (const f32x4*)&Bs[j][w * 32];
#pragma unroll
      for (int q = 0; q < 8; ++q) acc[q] += xv * br[q];
    }
  }
  float* sb = states + (size_t)blockIdx.x * 8192;
#pragma unroll
  for (int q = 0; q < 8; ++q)
#pragma unroll
    for (int c = 0; c < 4; ++c) {
      int n = w * 32 + q * 4 + c;
      sb[(size_t)n * 64 + p] = acc[q][c];
    }
}

// inter-chunk scan: states[bc] := s_prev ; s = s*cd + states
__global__ __launch_bounds__(256) void scan_k(const float* __restrict__ ca,
                                              float* __restrict__ states)
{
  const int b = blockIdx.x >> 10, h = (blockIdx.x >> 5) & 31, seg = blockIdx.x & 31;
  const int e = seg * 256 + threadIdx.x;
  float s = 0.f;
  for (int c = 0; c < CPB; ++c) {
    int bc = b * CPB + c;
    float cd = expf(ca[(size_t)(bc * 32 + h) * 128 + 127]);
    size_t idx = (size_t)(bc * 32 + h) * 8192 + e;
    float v = states[idx];
    states[idx] = s;
    s = s * cd + v;
  }
}

// fused y = y_intra + y_inter + D*x. One 32KB LDS buffer reused.
__global__ __launch_bounds__(256) void y_fused(const float* __restrict__ xbc,
                                               const float* __restrict__ dt,
                                               const float* __restrict__ ca,
                                               const float* __restrict__ CB,
                                               const float* __restrict__ Dvec,
                                               const float* __restrict__ states,
                                               float* __restrict__ ybuf)
{
  const int bc = blockIdx.x >> 5, h = blockIdx.x & 31;
  __shared__ float buf[128 * 64];
  __shared__ float cas[128];
  const int tid = threadIdx.x;
  if (tid < 128) cas[tid] = ca[(size_t)blockIdx.x * 128 + tid];
  for (int e = tid * 4; e < 8192; e += 1024) {
    int j = e >> 6;
    f32x4 xv = *(const f32x4*)(xbc + (size_t)(bc * 128 + j) * CONVDIM + h * 64 + (e & 63));
    float dj = dt[(size_t)(bc * 128 + j) * 32 + h];
    *(f32x4*)&buf[e] = xv * dj;
  }
  __syncthreads();
  const int i = tid >> 1, pb = (tid & 1) * 32;
  const float cai = cas[i];
  const float* cbrow = CB + (size_t)bc * 16384 + (size_t)i * 128;
  f32x4 acc[8] = {};
  for (int j = 0; j <= i; ++j) {
    float coeff = cbrow[j] * expf(cai - cas[j]);
    const f32x4* xr = (const f32x4*)&buf[j * 64 + pb];
#pragma unroll
    for (int q = 0; q < 8; ++q) acc[q] += coeff * xr[q];
  }
  __syncthreads();
  const float* sg = states + (size_t)blockIdx.x * 8192;
  for (int e = tid * 4; e < 8192; e += 1024)
    *(f32x4*)&buf[e] = *(const f32x4*)(sg + e);
  __syncthreads();
  const float* crow = xbc + (size_t)(bc * 128 + i) * CONVDIM + DIN + DSTATE;
  f32x4 acc2[8] = {};
  for (int n = 0; n < 128; ++n) {
    float cn = crow[n];
    const f32x4* sr = (const f32x4*)&buf[n * 64 + pb];
#pragma unroll
    for (int q = 0; q < 8; ++q) acc2[q] += cn * sr[q];
  }
  const float ei = expf(cai);
  const float dh = Dvec[h];
  const int tg = bc * 128 + i;
  float* yo = ybuf + (size_t)tg * DIN + h * 64 + pb;
  const float* xv = xbc + (size_t)tg * CONVDIM + h * 64 + pb;
#pragma unroll
  for (int q = 0; q < 8; ++q) {
    f32x4 x4 = *(const f32x4*)(xv + q * 4);
    *(f32x4*)(yo + q * 4) = acc[q] + ei * acc2[q] + dh * x4;
  }
}

// yg = y*silu(z); rms(2048) * mnorm_w -> fp16 (stride DIN)
__global__ __launch_bounds__(256) void gate_rms(const float* __restrict__ ybuf,
                                                const float* __restrict__ zx,
                                                const float* __restrict__ nw,
                                                f16* __restrict__ outh)
{
  const int row = blockIdx.x, tid = threadIdx.x;
  const float* yr = ybuf + (size_t)row * DIN;
  const float* zr = zx + (size_t)row * DPROJ;
  f32x4 y0 = *(const f32x4*)(yr + tid * 4);
  f32x4 y1 = *(const f32x4*)(yr + 1024 + tid * 4);
  f32x4 z0 = *(const f32x4*)(zr + tid * 4);
  f32x4 z1 = *(const f32x4*)(zr + 1024 + tid * 4);
  f32x4 g0, g1;
#pragma unroll
  for (int c = 0; c < 4; ++c) {
    g0[c] = y0[c] * (z0[c] / (1.f + expf(-z0[c])));
    g1[c] = y1[c] * (z1[c] / (1.f + expf(-z1[c])));
  }
  float ss = 0.f;
#pragma unroll
  for (int c = 0; c < 4; ++c) ss += g0[c] * g0[c] + g1[c] * g1[c];
  for (int o = 32; o; o >>= 1) ss += __shfl_down(ss, o);
  __shared__ float red[4];
  if ((tid & 63) == 0) red[tid >> 6] = ss;
  __syncthreads();
  ss = red[0] + red[1] + red[2] + red[3];
  const float sc = rsqrtf(ss * (1.f / 2048.f) + 1e-6f);
  f32x4 w0 = *(const f32x4*)(nw + tid * 4);
  f32x4 w1 = *(const f32x4*)(nw + 1024 + tid * 4);
  f16x4 h0, h1;
#pragma unroll
  for (int c = 0; c < 4; ++c) {
    h0[c] = (f16)(g0[c] * sc * w0[c]);
    h1[c] = (f16)(g1[c] * sc * w1[c]);
  }
  *(f16x4*)(outh + (size_t)row * DIN + tid * 4) = h0;
  *(f16x4*)(outh + (size_t)row * DIN + 1024 + tid * 4) = h1;
}

// ---------------- launcher ----------------
extern "C" void kernel_launch(void* const* d_in, const int* in_sizes, int n_in,
                              void* d_out, int out_size, void* d_ws, size_t ws_size,
                              hipStream_t stream)
{
  (void)in_sizes; (void)n_in; (void)out_size; (void)ws_size;
  const int*   tokens = (const int*)d_in[0];
  const float* emb    = (const float*)d_in[1];
  const float* lmb    = (const float*)d_in[2];
  const float* inw    = (const float*)d_in[3];
  const float* cw     = (const float*)d_in[4];
  const float* cbias  = (const float*)d_in[5];
  const float* dtb    = (const float*)d_in[6];
  const float* alog   = (const float*)d_in[7];
  const float* Dvec   = (const float*)d_in[8];
  const float* nw     = (const float*)d_in[9];
  const float* outw   = (const float*)d_in[10];
  const float* uw     = (const float*)d_in[11];
  const float* vw     = (const float*)d_in[12];
  const float* ow     = (const float*)d_in[13];

  char* ws = (char*)d_ws;
  size_t off = 0;
  auto alloc = [&](size_t bytes) { void* p = ws + off; off += (bytes + 255) & ~(size_t)255; return p; };
  f16* emb_h  = (f16*)alloc((size_t)VOCAB * DIM * 2);          // 65.5 MB
  f16* w_in   = (f16*)alloc((size_t)DPROJ * DIM * 2);          //  9.0 MB
  f16* w_out  = (f16*)alloc((size_t)DIM * DIN * 2);            //  4.2 MB
  f16* w_uv   = (f16*)alloc((size_t)2 * FFN * DIM * 2);        // 16.8 MB
  f16* w_o    = (f16*)alloc((size_t)DIM * FFN * 2);            //  8.4 MB
  float* xbuf = (float*)alloc((size_t)NTOK * DIM * 4);
  float* xn   = (float*)alloc((size_t)NTOK * DIM * 4);
  f16* xnh    = (f16*)alloc((size_t)NTOK * DIM * 2);
  f16* xh_lm  = (f16*)alloc((size_t)NTOK * DIM * 2);
  float* dtbuf = (float*)alloc((size_t)NTOK * NH * 4);
  float* cabuf = (float*)alloc((size_t)NCHUNK * NH * QLEN * 4);
  float* CBbuf = (float*)alloc((size_t)NCHUNK * QLEN * QLEN * 4);
  f16* abh    = (f16*)alloc((size_t)NTOK * FFN * 2);           // 33.6 MB

  // big transients live in d_out (fully overwritten by the final GEMM)
  char* ob = (char*)d_out;
  float* states = (float*)(ob);                    //  33.6 MB used
  float* zxb    = (float*)(ob + 134217728);        //  71.8 MB
  float* xbc    = (float*)(ob + 206045184);        //  37.7 MB
  float* ybuf   = (float*)(ob + 243793920);        //  33.6 MB
  float* parts  = (float*)(ob + 277348352);        //  split-K partials (<=67.1 MB)

  const int NRED = NTOK * DIM;   // 4,194,304

  cvt_f2h_k<<<4096, 256, 0, stream>>>(emb, emb_h, VOCAB * DIM);
  gather_k<<<NTOK, 256, 0, stream>>>(tokens, emb, xbuf);

  for (int it = 0; it < 2 * NLAYER; ++it) {
    const int li = it >> 1;
    if ((it & 1) == 0) {
      cvt_f2h_k<<<2048, 256, 0, stream>>>(inw + (size_t)li * DPROJ * DIM, w_in, DPROJ * DIM);
      cvt_f2h_k<<<1024, 256, 0, stream>>>(outw + (size_t)li * DIM * DIN, w_out, DIM * DIN);
      cvt_f2h_k<<<2048, 256, 0, stream>>>(uw + (size_t)li * FFN * DIM, w_uv, FFN * DIM);
      cvt_f2h_k<<<2048, 256, 0, stream>>>(vw + (size_t)li * FFN * DIM, w_uv + (size_t)FFN * DIM, FFN * DIM);
      cvt_f2h_k<<<2048, 256, 0, stream>>>(ow + (size_t)li * DIM * FFN, w_o, DIM * FFN);
    }
    // x = rms(x) ; mamba
    rms1024<<<NTOK, 256, 0, stream>>>(xbuf, xn, xnh);
    gemm_p2<<<dim3((DPROJ + 255) / 256, NTOK / 256, 1), 512, SMEM2, stream>>>(
        xnh, w_in, zxb, nullptr, DPROJ, DIM, DIM, DIM, DPROJ);
    conv_silu2<<<576, 256, 0, stream>>>(zxb, cw + (size_t)li * CONVDIM * DCONV,
                                        cbias + (size_t)li * CONVDIM, xbc);
    dt_ca<<<NCHUNK * NH, 128, 0, stream>>>(zxb, dtb + li * NH, alog + li * NH, dtbuf, cabuf);
    cb_kernel<<<NCHUNK, 256, 0, stream>>>(xbc, CBbuf);
    states_k<<<NCHUNK * NH, 256, 0, stream>>>(xbc, dtbuf, cabuf, states);
    scan_k<<<2048, 256, 0, stream>>>(cabuf, states);
    y_fused<<<NCHUNK * NH, 256, 0, stream>>>(xbc, dtbuf, cabuf, CBbuf,
                                             Dvec + li * NH, states, ybuf);
    gate_rms<<<NTOK, 256, 0, stream>>>(ybuf, zxb, nw + (size_t)li * DIN, abh);
    // out_proj: split-K x4 (K=2048 -> Ksub=512), deterministic reduce adds residual xn
    gemm_p2<<<dim3(DIM / 256, NTOK / 256, 4), 512, SMEM2, stream>>>(
        abh, w_out, parts, nullptr, DIM, DIN / 4, DIN, DIN, DIM);
    reduce_k<<<4096, 256, 0, stream>>>(parts, xn, xbuf, 4, NRED);
    // x = rms(x) ; gated FFN
    rms1024<<<NTOK, 256, 0, stream>>>(xbuf, xn, xnh);
    gemm_uv2<<<dim3(FFN / 128, NTOK / 256, 1), 512, SMEM2, stream>>>(
        xnh, w_uv, w_uv + (size_t)FFN * DIM, abh);
    // o_proj: split-K x4 (K=4096 -> Ksub=1024)
    gemm_p2<<<dim3(DIM / 256, NTOK / 256, 4), 512, SMEM2, stream>>>(
        abh, w_o, parts, nullptr, DIM, FFN / 4, FFN, FFN, DIM);
    reduce_k<<<4096, 256, 0, stream>>>(parts, xn, xbuf, 4, NRED);
  }

  // lm head (single fp16)
  cvt_f2h_k<<<4096, 256, 0, stream>>>(xbuf, xh_lm, NTOK * DIM);
  gemm_p2<<<dim3(VOCAB / 256, NTOK / 256, 1), 512, SMEM2, stream>>>(
      xh_lm, emb_h, (float*)d_out, lmb, VOCAB, DIM, DIM, DIM, VOCAB);
}

// Round 10
// 4495.818 us; speedup vs baseline: 1.0629x; 1.0629x over previous
//
#include <hip/hip_runtime.h>
#include <hip/hip_bf16.h>

// ---------------- problem constants ----------------
#define BSZ 2
#define LSEQ 2048
#define DIM 1024
#define VOCAB 32000
#define NLAYER 4
#define DSTATE 128
#define DCONV 4
#define HEADDIM 64
#define DIN 2048
#define NH 32
#define CONVDIM 2304          // DIN + 2*DSTATE
#define DPROJ 4384            // 2*DIN + 2*DSTATE + NH
#define FFN 4096
#define QLEN 128
#define NTOK 4096             // BSZ*LSEQ
#define NCHUNK 32             // NTOK/QLEN
#define CPB 16                // chunks per batch

#define SMEM_BYTES 147456     // gemm_p: 3 x (A 32KB + B 16KB)
#define SMEM2 131072          // gemm_p2: 2 x (A 32KB + B 32KB)

using f32x4 = __attribute__((ext_vector_type(4))) float;
using f16   = _Float16;
using f16x4 = __attribute__((ext_vector_type(4))) _Float16;
using f16x8 = __attribute__((ext_vector_type(8))) _Float16;

__device__ __forceinline__ void gld16(const void* g, void* l) {
  __builtin_amdgcn_global_load_lds(
      (const __attribute__((address_space(1))) unsigned int*)g,
      (__attribute__((address_space(3))) unsigned int*)l, 16, 0, 0);
}

// Tile swizzle: XCD-contiguous + column-chunked (8 bx per chunk, sweep all by)
__device__ __forceinline__ void swz_tiles(int& bx, int& by) {
  const int nx = gridDim.x, ny = gridDim.y;
  const int nwg = nx * ny;
  int bid = blockIdx.y * nx + blockIdx.x;
  if ((nwg & 7) == 0) bid = (bid & 7) * (nwg >> 3) + (bid >> 3);
  const int CW = 8;
  const int nchx = nx / CW;
  const int per = CW * ny;
  const int ch = bid / per;
  if (ch < nchx) {
    int wi = bid - ch * per;
    bx = ch * CW + (wi & (CW - 1));
    by = wi / CW;
  } else {
    int tb = bid - nchx * per;
    int tw = nx - nchx * CW;
    bx = nchx * CW + (tb % tw);
    by = tb / tw;
  }
}

// ---------------- pipelined fp16 GEMM: 256x128 tile, BK=64, 3-buffer counted-vmcnt ----------------
// MODE 0: C(f32) = A * Bu^T ; split-K via blockIdx.z (Cf advanced z*M*ldc)
// MODE 2: G(f16) = (A Bu^T) .* (A Bv^T)
// Ledger: 6 gld16/thread/stage; in-loop stage(T+2) then vmcnt(12) retires tile T.
// Tail vmcnt(6), vmcnt(0). XOR swizzle slot=g^(row&7), pre-swizzled global source.
template <int MODE>
__global__ __launch_bounds__(512, 2) void gemm_p(
    const f16* __restrict__ A, const f16* __restrict__ Bu, const f16* __restrict__ Bv,
    float* __restrict__ Cf, f16* __restrict__ Gh, const float* __restrict__ bias,
    int N, int Ksub, int lda, int ldb, int ldc)
{
  extern __shared__ char smem[];
  const int tid  = threadIdx.x;
  const int lane = tid & 63;
  const int wid  = tid >> 6;
  int bx, by; swz_tiles(bx, by);
  const int m0 = by * 256;
  const int n0 = bx * 128;
  const size_t kbase = (size_t)blockIdx.z * Ksub;
  if (gridDim.z > 1) Cf += (size_t)blockIdx.z * (size_t)gridDim.y * 256 * ldc;

  const int NT  = Ksub >> 6;
  const int NTT = (MODE == 2) ? 2 * NT : NT;

  int arA[4], acA[4];
#pragma unroll
  for (int L = 0; L < 4; ++L) {
    int q = L * 512 + tid;
    int row = q >> 3;
    arA[L] = m0 + row;
    acA[L] = ((q & 7) ^ (row & 7)) << 3;
  }
  int brB[2], bcB[2];
#pragma unroll
  for (int L = 0; L < 2; ++L) {
    int q = L * 512 + tid;
    int row = q >> 3;
    int r = n0 + row; if (r > N - 1) r = N - 1;
    brB[L] = r;
    bcB[L] = ((q & 7) ^ (row & 7)) << 3;
  }

  auto stage = [&](int tt) {
    const int b = tt - (tt / 3) * 3;
    char* Ad = smem + b * 32768;
    char* Bd = smem + 98304 + b * 16384;
    int ta = tt;
    const f16* Bp = Bu;
    if (MODE == 2 && tt >= NT) { ta = tt - NT; Bp = Bv; }
    const int kb = ta << 6;
#pragma unroll
    for (int L = 0; L < 4; ++L)
      gld16(A + (size_t)arA[L] * lda + kbase + kb + acA[L], Ad + (L * 512 + tid) * 16);
#pragma unroll
    for (int L = 0; L < 2; ++L)
      gld16(Bp + (size_t)brB[L] * ldb + kbase + kb + bcB[L], Bd + (L * 512 + tid) * 16);
  };

  const int wm = (wid >> 1) << 6;
  const int wn = (wid & 1) << 6;
  const int fr = lane & 15;
  const int kg = lane >> 4;

  f32x4 accu[4][4] = {};
  f32x4 accv[4][4] = {};

  stage(0);
  stage(1);

  for (int t = 0; t < NTT; ++t) {
    const int b = t - (t / 3) * 3;
    if (t + 2 < NTT) {
      stage(t + 2);
      asm volatile("s_waitcnt vmcnt(12)" ::: "memory");
    } else if (t + 1 < NTT) {
      asm volatile("s_waitcnt vmcnt(6)" ::: "memory");
    } else {
      asm volatile("s_waitcnt vmcnt(0)" ::: "memory");
    }
    __builtin_amdgcn_s_barrier();
    asm volatile("" ::: "memory");
    const f16* Ab = (const f16*)(smem + b * 32768);
    const f16* Bb = (const f16*)(smem + 98304 + b * 16384);
#pragma unroll
    for (int s = 0; s < 2; ++s) {
      f16x8 af[4], bf[4];
#pragma unroll
      for (int j = 0; j < 4; ++j) {
        int row = wm + j * 16 + fr;
        int g = kg + s * 4;
        af[j] = *(const f16x8*)&Ab[row * 64 + ((g ^ (row & 7)) << 3)];
      }
#pragma unroll
      for (int i = 0; i < 4; ++i) {
        int row = wn + i * 16 + fr;
        int g = kg + s * 4;
        bf[i] = *(const f16x8*)&Bb[row * 64 + ((g ^ (row & 7)) << 3)];
      }
      if (MODE == 2 && t >= NT) {
#pragma unroll
        for (int i = 0; i < 4; ++i)
#pragma unroll
          for (int j = 0; j < 4; ++j)
            accv[i][j] = __builtin_amdgcn_mfma_f32_16x16x32_f16(bf[i], af[j], accv[i][j], 0, 0, 0);
      } else {
#pragma unroll
        for (int i = 0; i < 4; ++i)
#pragma unroll
          for (int j = 0; j < 4; ++j)
            accu[i][j] = __builtin_amdgcn_mfma_f32_16x16x32_f16(bf[i], af[j], accu[i][j], 0, 0, 0);
      }
    }
    asm volatile("" ::: "memory");
    __builtin_amdgcn_s_barrier();
    asm volatile("" ::: "memory");
  }

  const int c4 = kg << 2;
  if constexpr (MODE == 0) {
#pragma unroll
    for (int i = 0; i < 4; ++i) {
      const int col = n0 + wn + i * 16 + c4;
      if (col >= N) continue;
      f32x4 bv = bias ? *(const f32x4*)(bias + col) : f32x4{0, 0, 0, 0};
#pragma unroll
      for (int j = 0; j < 4; ++j) {
        const int row = m0 + wm + j * 16 + fr;
        *(f32x4*)(Cf + (size_t)row * ldc + col) = accu[i][j] + bv;
      }
    }
  } else {
#pragma unroll
    for (int i = 0; i < 4; ++i) {
      const int col = n0 + wn + i * 16 + c4;
#pragma unroll
      for (int j = 0; j < 4; ++j) {
        const int row = m0 + wm + j * 16 + fr;
        f16x4 h;
#pragma unroll
        for (int r = 0; r < 4; ++r)
          h[r] = (f16)(accu[i][j][r] * accv[i][j][r]);
        *(f16x4*)(Gh + (size_t)row * ldc + col) = h;
      }
    }
  }
}

// ---------------- pipelined fp16 GEMM: 256x256 tile, BK=64, 2-buffer (lm-head) ----------------
__global__ __launch_bounds__(512, 2) void gemm_p2(
    const f16* __restrict__ A, const f16* __restrict__ B,
    float* __restrict__ Cf, const float* __restrict__ bias,
    int N, int Ksub, int lda, int ldb, int ldc)
{
  extern __shared__ char smem[];
  const int tid  = threadIdx.x;
  const int lane = tid & 63;
  const int wid  = tid >> 6;
  int bx, by; swz_tiles(bx, by);
  const int m0 = by * 256;
  const int n0 = bx * 256;
  const size_t kbase = (size_t)blockIdx.z * Ksub;
  if (gridDim.z > 1) Cf += (size_t)blockIdx.z * (size_t)gridDim.y * 256 * ldc;
  const int NT = Ksub >> 6;

  int arA[4], acA[4], brB[4], bcB[4];
#pragma unroll
  for (int L = 0; L < 4; ++L) {
    int q = L * 512 + tid;
    int row = q >> 3;
    arA[L] = m0 + row;
    acA[L] = ((q & 7) ^ (row & 7)) << 3;
    int r = n0 + row; if (r > N - 1) r = N - 1;
    brB[L] = r;
    bcB[L] = acA[L];
  }

  auto stage = [&](int tt) {
    const int b = tt & 1;
    char* Ad = smem + b * 65536;
    char* Bd = Ad + 32768;
    const int kb = tt << 6;
#pragma unroll
    for (int L = 0; L < 4; ++L)
      gld16(A + (size_t)arA[L] * lda + kbase + kb + acA[L], Ad + (L * 512 + tid) * 16);
#pragma unroll
    for (int L = 0; L < 4; ++L)
      gld16(B + (size_t)brB[L] * ldb + kbase + kb + bcB[L], Bd + (L * 512 + tid) * 16);
  };

  const int wm = (wid >> 2) << 7;
  const int wn = (wid & 3) << 6;
  const int fr = lane & 15;
  const int kg = lane >> 4;

  f32x4 acc[4][8] = {};

  stage(0);

  for (int t = 0; t < NT; ++t) {
    if (t + 1 < NT) {
      stage(t + 1);
      asm volatile("s_waitcnt vmcnt(8)" ::: "memory");
    } else {
      asm volatile("s_waitcnt vmcnt(0)" ::: "memory");
    }
    __builtin_amdgcn_s_barrier();
    asm volatile("" ::: "memory");
    const f16* Ab = (const f16*)(smem + (t & 1) * 65536);
    const f16* Bb = Ab + 16384;
#pragma unroll
    for (int s = 0; s < 2; ++s) {
      const int g = kg + s * 4;
      f16x8 af[8], bf[4];
#pragma unroll
      for (int j = 0; j < 8; ++j) {
        int row = wm + j * 16 + fr;
        af[j] = *(const f16x8*)&Ab[row * 64 + ((g ^ (row & 7)) << 3)];
      }
#pragma unroll
      for (int i = 0; i < 4; ++i) {
        int row = wn + i * 16 + fr;
        bf[i] = *(const f16x8*)&Bb[row * 64 + ((g ^ (row & 7)) << 3)];
      }
#pragma unroll
      for (int i = 0; i < 4; ++i)
#pragma unroll
        for (int j = 0; j < 8; ++j)
          acc[i][j] = __builtin_amdgcn_mfma_f32_16x16x32_f16(bf[i], af[j], acc[i][j], 0, 0, 0);
    }
    asm volatile("" ::: "memory");
    __builtin_amdgcn_s_barrier();
    asm volatile("" ::: "memory");
  }

  const int c4 = kg << 2;
#pragma unroll
  for (int i = 0; i < 4; ++i) {
    const int col = n0 + wn + i * 16 + c4;
    if (col >= N) continue;
    f32x4 bv = bias ? *(const f32x4*)(bias + col) : f32x4{0, 0, 0, 0};
#pragma unroll
    for (int j = 0; j < 8; ++j) {
      const int row = m0 + wm + j * 16 + fr;
      *(f32x4*)(Cf + (size_t)row * ldc + col) = acc[i][j] + bv;
    }
  }
}

// fused split-K reduce + rms: x = resid + sum parts; if DORMS write xn=f32 rms(x),
// outh=f16 rms(x); else outh=f16(x). One block per row.
template <bool DORMS>
__global__ __launch_bounds__(256) void reduce_rms(const float* __restrict__ parts,
                                                  const float* __restrict__ resid,
                                                  float* __restrict__ xn,
                                                  f16* __restrict__ outh, int np)
{
  const int row = blockIdx.x, tid = threadIdx.x;
  const size_t base = (size_t)row * DIM + tid * 4;
  f32x4 s = *(const f32x4*)(resid + base);
  for (int p = 0; p < np; ++p)
    s += *(const f32x4*)(parts + (size_t)p * (NTOK * DIM) + base);
  if constexpr (!DORMS) {
    f16x4 h;
#pragma unroll
    for (int c = 0; c < 4; ++c) h[c] = (f16)s[c];
    *(f16x4*)(outh + base) = h;
    return;
  }
  float ss = s[0] * s[0] + s[1] * s[1] + s[2] * s[2] + s[3] * s[3];
  for (int o = 32; o; o >>= 1) ss += __shfl_down(ss, o);
  __shared__ float red[4];
  if ((tid & 63) == 0) red[tid >> 6] = ss;
  __syncthreads();
  ss = red[0] + red[1] + red[2] + red[3];
  const float sc = rsqrtf(ss * (1.f / 1024.f) + 1e-6f);
  f32x4 o4 = s * sc;
  *(f32x4*)(xn + base) = o4;
  f16x4 h;
#pragma unroll
  for (int c = 0; c < 4; ++c) h[c] = (f16)o4[c];
  *(f16x4*)(outh + base) = h;
}

// ---------------- small kernels ----------------
__global__ __launch_bounds__(256) void cvt_f2h_k(const float* __restrict__ src,
                                                 f16* __restrict__ dst, int n)
{
  for (size_t i = ((size_t)blockIdx.x * 256 + threadIdx.x) * 4; i < (size_t)n;
       i += (size_t)gridDim.x * 1024) {
    f32x4 v = *(const f32x4*)(src + i);
    f16x4 o;
#pragma unroll
    for (int c = 0; c < 4; ++c) o[c] = (f16)v[c];
    *(f16x4*)(dst + i) = o;
  }
}

// merged per-layer weight conversion: 5 arrays, range-dispatched (18720 blocks)
__global__ __launch_bounds__(256) void cvt_wts(
    const float* __restrict__ inw, const float* __restrict__ outw,
    const float* __restrict__ uw, const float* __restrict__ vw,
    const float* __restrict__ ow,
    f16* __restrict__ w_in, f16* __restrict__ w_out,
    f16* __restrict__ w_uv, f16* __restrict__ w_o)
{
  const int b = blockIdx.x;
  const float* src; f16* dst; int base;
  if (b < 4384)       { src = inw;  dst = w_in;                       base = 0; }
  else if (b < 6432)  { src = outw; dst = w_out;                      base = 4384; }
  else if (b < 10528) { src = uw;   dst = w_uv;                       base = 6432; }
  else if (b < 14624) { src = vw;   dst = w_uv + (size_t)FFN * DIM;   base = 10528; }
  else                { src = ow;   dst = w_o;                        base = 14624; }
  const size_t i = ((size_t)(b - base) * 256 + threadIdx.x) * 4;
  f32x4 v = *(const f32x4*)(src + i);
  f16x4 o;
#pragma unroll
  for (int c = 0; c < 4; ++c) o[c] = (f16)v[c];
  *(f16x4*)(dst + i) = o;
}

__global__ __launch_bounds__(256) void gather_k(const int* __restrict__ tok,
                                                const float* __restrict__ emb,
                                                float* __restrict__ x)
{
  const int row = blockIdx.x;
  const int t = tok[row];
  const f32x4* s = (const f32x4*)(emb + (size_t)t * DIM);
  f32x4* d = (f32x4*)(x + (size_t)row * DIM);
  d[threadIdx.x] = s[threadIdx.x];
}

// rms over 1024; writes f32 and fp16 copies (used once, after gather)
__global__ __launch_bounds__(256) void rms1024(const float* __restrict__ in,
                                               float* __restrict__ outf,
                                               f16* __restrict__ outh)
{
  const int row = blockIdx.x, tid = threadIdx.x;
  f32x4 v = ((const f32x4*)(in + (size_t)row * DIM))[tid];
  float ss = v[0] * v[0] + v[1] * v[1] + v[2] * v[2] + v[3] * v[3];
  for (int o = 32; o; o >>= 1) ss += __shfl_down(ss, o);
  __shared__ float red[4];
  if ((tid & 63) == 0) red[tid >> 6] = ss;
  __syncthreads();
  ss = red[0] + red[1] + red[2] + red[3];
  const float sc = rsqrtf(ss * (1.f / 1024.f) + 1e-6f);
  f32x4 o4 = v * sc;
  ((f32x4*)(outf + (size_t)row * DIM))[tid] = o4;
  f16x4 h;
#pragma unroll
  for (int c = 0; c < 4; ++c) h[c] = (f16)o4[c];
  ((f16x4*)(outh + (size_t)row * DIM))[tid] = h;
}

// merged: blocks [0,576) = causal conv+silu (sliding window); [576,1088) = dt/ca (2 units/block)
__global__ __launch_bounds__(256) void convdt(const float* __restrict__ zx,
                                              const float* __restrict__ cw,
                                              const float* __restrict__ cbias,
                                              const float* __restrict__ dtb,
                                              const float* __restrict__ alog,
                                              float* __restrict__ xbc,
                                              float* __restrict__ dt,
                                              float* __restrict__ ca)
{
  if (blockIdx.x < 576) {
    const int sid = blockIdx.x * 256 + threadIdx.x;
    const int c0 = (sid % 576) * 4;
    const int t0 = (sid / 576) * 16;
    float w[4][4], bs[4];
#pragma unroll
    for (int cc = 0; cc < 4; ++cc) {
      f32x4 wv = *(const f32x4*)(cw + (size_t)(c0 + cc) * 4);
      w[cc][0] = wv[0]; w[cc][1] = wv[1]; w[cc][2] = wv[2]; w[cc][3] = wv[3];
      bs[cc] = cbias[c0 + cc];
    }
    const int l0 = t0 & (LSEQ - 1);
    f32x4 x3 = {0, 0, 0, 0}, x2 = {0, 0, 0, 0}, x1 = {0, 0, 0, 0};
    if (l0 != 0) {
      x3 = *(const f32x4*)(zx + (size_t)(t0 - 3) * DPROJ + DIN + c0);
      x2 = *(const f32x4*)(zx + (size_t)(t0 - 2) * DPROJ + DIN + c0);
      x1 = *(const f32x4*)(zx + (size_t)(t0 - 1) * DPROJ + DIN + c0);
    }
    for (int i = 0; i < 16; ++i) {
      const int t = t0 + i;
      f32x4 xc = *(const f32x4*)(zx + (size_t)t * DPROJ + DIN + c0);
      f32x4 o;
#pragma unroll
      for (int cc = 0; cc < 4; ++cc) {
        float a = bs[cc] + x3[cc] * w[cc][0] + x2[cc] * w[cc][1] +
                  x1[cc] * w[cc][2] + xc[cc] * w[cc][3];
        o[cc] = a / (1.f + expf(-a));
      }
      *(f32x4*)(xbc + (size_t)t * CONVDIM + c0) = o;
      x3 = x2; x2 = x1; x1 = xc;
    }
  } else {
    const int loc = (threadIdx.x >> 7) * 128;
    const int u = (blockIdx.x - 576) * 2 + (threadIdx.x >> 7);
    const int bc = u >> 5, h = u & 31, q = threadIdx.x & 127;
    const int t = bc * 128 + q;
    float raw = zx[(size_t)t * DPROJ + (DIN + CONVDIM) + h] + dtb[h];
    float d = raw > 20.f ? raw : log1pf(expf(raw));
    dt[t * 32 + h] = d;
    float a = -expf(alog[h]) * d;
    __shared__ float s[256];
    s[loc + q] = a;
    __syncthreads();
    for (int off = 1; off < 128; off <<= 1) {
      float v = (q >= off) ? s[loc + q - off] : 0.f;
      __syncthreads();
      s[loc + q] += v;
      __syncthreads();
    }
    ca[(size_t)u * 128 + q] = s[loc + q];
  }
}

// CB[bc][i][j] = sum_n C[i,n]*B[j,n]
__global__ __launch_bounds__(256) void cb_kernel(const float* __restrict__ xbc,
                                                 float* __restrict__ CB)
{
  const int bc = blockIdx.x;
  __shared__ float Bs[128][32], Cs[128][32];
  float acc[8][8] = {};
  const int ti = threadIdx.x >> 4, tj = threadIdx.x & 15;
  for (int n0 = 0; n0 < 128; n0 += 32) {
    __syncthreads();
    for (int e = threadIdx.x; e < 4096; e += 256) {
      int r = e >> 5, c = e & 31;
      const float* row = xbc + (size_t)(bc * 128 + r) * CONVDIM + DIN;
      Bs[r][c] = row[n0 + c];
      Cs[r][c] = row[DSTATE + n0 + c];
    }
    __syncthreads();
    for (int n = 0; n < 32; ++n) {
      float cv[8], bv[8];
#pragma unroll
      for (int ii = 0; ii < 8; ++ii) cv[ii] = Cs[ti * 8 + ii][n];
#pragma unroll
      for (int jj = 0; jj < 8; ++jj) bv[jj] = Bs[tj * 8 + jj][n];
#pragma unroll
      for (int ii = 0; ii < 8; ++ii)
#pragma unroll
        for (int jj = 0; jj < 8; ++jj) acc[ii][jj] += cv[ii] * bv[jj];
    }
  }
  for (int ii = 0; ii < 8; ++ii)
    for (int jj = 0; jj < 8; ++jj)
      CB[(size_t)bc * 16384 + (size_t)(ti * 8 + ii) * 128 + (tj * 8 + jj)] = acc[ii][jj];
}

// states[n][p] = sum_j exp(ca_last-ca_j)*dt_j*B[j][n]*x[j][p]   (layout [bc][h][n][p])
__global__ __launch_bounds__(256) void states_k(const float* __restrict__ xbc,
                                                const float* __restrict__ dt,
                                                const float* __restrict__ ca,
                                                float* __restrict__ states)
{
  const int bc = blockIdx.x >> 5, h = blockIdx.x & 31;
  __shared__ float xw[128][64];
  __shared__ float Bs[32][128];
  __shared__ float warr[128];
  const int tid = threadIdx.x;
  if (tid < 128) {
    float cv = ca[(size_t)blockIdx.x * 128 + tid];
    float clast = ca[(size_t)blockIdx.x * 128 + 127];
    warr[tid] = expf(clast - cv) * dt[(size_t)(bc * 128 + tid) * 32 + h];
  }
  __syncthreads();
  for (int e = tid * 4; e < 8192; e += 1024) {
    int j = e >> 6, p = e & 63;
    f32x4 xv = *(const f32x4*)(xbc + (size_t)(bc * 128 + j) * CONVDIM + h * 64 + p);
    *(f32x4*)&xw[j][p] = xv * warr[j];
  }
  const int w = tid >> 6, p = tid & 63;
  f32x4 acc[8] = {};
  for (int jc = 0; jc < 128; jc += 32) {
    __syncthreads();
    for (int e = tid * 4; e < 4096; e += 1024) {
      int j = e >> 7, n = e & 127;
      *(f32x4*)&Bs[j][n] =
          *(const f32x4*)(xbc + (size_t)(bc * 128 + jc + j) * CONVDIM + DIN + n);
    }
    __syncthreads();
    for (int j = 0; j < 32; ++j) {
      float xv = xw[jc + j][p];
      const f32x4* br = (const f32x4*)&Bs[j][w * 32];
#pragma unroll
      for (int q = 0; q < 8; ++q) acc[q] += xv * br[q];
    }
  }
  float* sb = states + (size_t)blockIdx.x * 8192;
#pragma unroll
  for (int q = 0; q < 8; ++q)
#pragma unroll
    for (int c = 0; c < 4; ++c) {
      int n = w * 32 + q * 4 + c;
      sb[(size_t)n * 64 + p] = acc[q][c];
    }
}

// inter-chunk scan: states[bc] := s_prev ; s = s*cd + states
__global__ __launch_bounds__(256) void scan_k(const float* __restrict__ ca,
                                              float* __restrict__ states)
{
  const int b = blockIdx.x >> 10, h = (blockIdx.x >> 5) & 31, seg = blockIdx.x & 31;
  const int e = seg * 256 + threadIdx.x;
  float s = 0.f;
  for (int c = 0; c < CPB; ++c) {
    int bc = b * CPB + c;
    float cd = expf(ca[(size_t)(bc * 32 + h) * 128 + 127]);
    size_t idx = (size_t)(bc * 32 + h) * 8192 + e;
    float v = states[idx];
    states[idx] = s;
    s = s * cd + v;
  }
}

// fused y = y_intra + y_inter + D*x. One 32KB LDS buffer reused.
__global__ __launch_bounds__(256) void y_fused(const float* __restrict__ xbc,
                                               const float* __restrict__ dt,
                                               const float* __restrict__ ca,
                                               const float* __restrict__ CB,
                                               const float* __restrict__ Dvec,
                                               const float* __restrict__ states,
                                               float* __restrict__ ybuf)
{
  const int bc = blockIdx.x >> 5, h = blockIdx.x & 31;
  __shared__ float buf[128 * 64];
  __shared__ float cas[128];
  const int tid = threadIdx.x;
  if (tid < 128) cas[tid] = ca[(size_t)blockIdx.x * 128 + tid];
  for (int e = tid * 4; e < 8192; e += 1024) {
    int j = e >> 6;
    f32x4 xv = *(const f32x4*)(xbc + (size_t)(bc * 128 + j) * CONVDIM + h * 64 + (e & 63));
    float dj = dt[(size_t)(bc * 128 + j) * 32 + h];
    *(f32x4*)&buf[e] = xv * dj;
  }
  __syncthreads();
  const int i = tid >> 1, pb = (tid & 1) * 32;
  const float cai = cas[i];
  const float* cbrow = CB + (size_t)bc * 16384 + (size_t)i * 128;
  f32x4 acc[8] = {};
  for (int j = 0; j <= i; ++j) {
    float coeff = cbrow[j] * expf(cai - cas[j]);
    const f32x4* xr = (const f32x4*)&buf[j * 64 + pb];
#pragma unroll
    for (int q = 0; q < 8; ++q) acc[q] += coeff * xr[q];
  }
  __syncthreads();
  const float* sg = states + (size_t)blockIdx.x * 8192;
  for (int e = tid * 4; e < 8192; e += 1024)
    *(f32x4*)&buf[e] = *(const f32x4*)(sg + e);
  __syncthreads();
  const float* crow = xbc + (size_t)(bc * 128 + i) * CONVDIM + DIN + DSTATE;
  f32x4 acc2[8] = {};
  for (int n = 0; n < 128; ++n) {
    float cn = crow[n];
    const f32x4* sr = (const f32x4*)&buf[n * 64 + pb];
#pragma unroll
    for (int q = 0; q < 8; ++q) acc2[q] += cn * sr[q];
  }
  const float ei = expf(cai);
  const float dh = Dvec[h];
  const int tg = bc * 128 + i;
  float* yo = ybuf + (size_t)tg * DIN + h * 64 + pb;
  const float* xv = xbc + (size_t)tg * CONVDIM + h * 64 + pb;
#pragma unroll
  for (int q = 0; q < 8; ++q) {
    f32x4 x4 = *(const f32x4*)(xv + q * 4);
    *(f32x4*)(yo + q * 4) = acc[q] + ei * acc2[q] + dh * x4;
  }
}

// yg = y*silu(z); rms(2048) * mnorm_w -> fp16 (stride DIN)
__global__ __launch_bounds__(256) void gate_rms(const float* __restrict__ ybuf,
                                                const float* __restrict__ zx,
                                                const float* __restrict__ nw,
                                                f16* __restrict__ outh)
{
  const int row = blockIdx.x, tid = threadIdx.x;
  const float* yr = ybuf + (size_t)row * DIN;
  const float* zr = zx + (size_t)row * DPROJ;
  f32x4 y0 = *(const f32x4*)(yr + tid * 4);
  f32x4 y1 = *(const f32x4*)(yr + 1024 + tid * 4);
  f32x4 z0 = *(const f32x4*)(zr + tid * 4);
  f32x4 z1 = *(const f32x4*)(zr + 1024 + tid * 4);
  f32x4 g0, g1;
#pragma unroll
  for (int c = 0; c < 4; ++c) {
    g0[c] = y0[c] * (z0[c] / (1.f + expf(-z0[c])));
    g1[c] = y1[c] * (z1[c] / (1.f + expf(-z1[c])));
  }
  float ss = 0.f;
#pragma unroll
  for (int c = 0; c < 4; ++c) ss += g0[c] * g0[c] + g1[c] * g1[c];
  for (int o = 32; o; o >>= 1) ss += __shfl_down(ss, o);
  __shared__ float red[4];
  if ((tid & 63) == 0) red[tid >> 6] = ss;
  __syncthreads();
  ss = red[0] + red[1] + red[2] + red[3];
  const float sc = rsqrtf(ss * (1.f / 2048.f) + 1e-6f);
  f32x4 w0 = *(const f32x4*)(nw + tid * 4);
  f32x4 w1 = *(const f32x4*)(nw + 1024 + tid * 4);
  f16x4 h0, h1;
#pragma unroll
  for (int c = 0; c < 4; ++c) {
    h0[c] = (f16)(g0[c] * sc * w0[c]);
    h1[c] = (f16)(g1[c] * sc * w1[c]);
  }
  *(f16x4*)(outh + (size_t)row * DIN + tid * 4) = h0;
  *(f16x4*)(outh + (size_t)row * DIN + 1024 + tid * 4) = h1;
}

// ---------------- launcher ----------------
extern "C" void kernel_launch(void* const* d_in, const int* in_sizes, int n_in,
                              void* d_out, int out_size, void* d_ws, size_t ws_size,
                              hipStream_t stream)
{
  (void)in_sizes; (void)n_in; (void)out_size; (void)ws_size;
  const int*   tokens = (const int*)d_in[0];
  const float* emb    = (const float*)d_in[1];
  const float* lmb    = (const float*)d_in[2];
  const float* inw    = (const float*)d_in[3];
  const float* cw     = (const float*)d_in[4];
  const float* cbias  = (const float*)d_in[5];
  const float* dtb    = (const float*)d_in[6];
  const float* alog   = (const float*)d_in[7];
  const float* Dvec   = (const float*)d_in[8];
  const float* nw     = (const float*)d_in[9];
  const float* outw   = (const float*)d_in[10];
  const float* uw     = (const float*)d_in[11];
  const float* vw     = (const float*)d_in[12];
  const float* ow     = (const float*)d_in[13];

  char* ws = (char*)d_ws;
  size_t off = 0;
  auto alloc = [&](size_t bytes) { void* p = ws + off; off += (bytes + 255) & ~(size_t)255; return p; };
  f16* emb_h  = (f16*)alloc((size_t)VOCAB * DIM * 2);          // 65.5 MB
  f16* w_in   = (f16*)alloc((size_t)DPROJ * DIM * 2);          //  9.0 MB
  f16* w_out  = (f16*)alloc((size_t)DIM * DIN * 2);            //  4.2 MB
  f16* w_uv   = (f16*)alloc((size_t)2 * FFN * DIM * 2);        // 16.8 MB
  f16* w_o    = (f16*)alloc((size_t)DIM * FFN * 2);            //  8.4 MB
  float* xbuf = (float*)alloc((size_t)NTOK * DIM * 4);
  float* xn   = (float*)alloc((size_t)NTOK * DIM * 4);
  f16* xnh    = (f16*)alloc((size_t)NTOK * DIM * 2);
  f16* xh_lm  = (f16*)alloc((size_t)NTOK * DIM * 2);
  float* dtbuf = (float*)alloc((size_t)NTOK * NH * 4);
  float* cabuf = (float*)alloc((size_t)NCHUNK * NH * QLEN * 4);
  float* CBbuf = (float*)alloc((size_t)NCHUNK * QLEN * QLEN * 4);
  f16* abh    = (f16*)alloc((size_t)NTOK * FFN * 2);           // 33.6 MB

  // big transients live in d_out (fully overwritten by the final GEMM)
  char* ob = (char*)d_out;
  float* states = (float*)(ob);                    //  33.6 MB used
  float* zxb    = (float*)(ob + 134217728);        //  71.8 MB
  float* xbc    = (float*)(ob + 206045184);        //  37.7 MB
  float* ybuf   = (float*)(ob + 243793920);        //  33.6 MB
  float* parts  = (float*)(ob + 277348352);        //  split-K partials (33.6 MB)

  cvt_f2h_k<<<4096, 256, 0, stream>>>(emb, emb_h, VOCAB * DIM);
  gather_k<<<NTOK, 256, 0, stream>>>(tokens, emb, xbuf);
  rms1024<<<NTOK, 256, 0, stream>>>(xbuf, xn, xnh);

  for (int it = 0; it < 2 * NLAYER; ++it) {
    const int li = it >> 1;
    if ((it & 1) == 0) {
      cvt_wts<<<18720, 256, 0, stream>>>(
          inw + (size_t)li * DPROJ * DIM, outw + (size_t)li * DIM * DIN,
          uw + (size_t)li * FFN * DIM, vw + (size_t)li * FFN * DIM,
          ow + (size_t)li * DIM * FFN, w_in, w_out, w_uv, w_o);
    }
    // mamba (input xnh = rms'd stream)
    gemm_p<0><<<dim3((DPROJ + 127) / 128, NTOK / 256, 1), 512, SMEM_BYTES, stream>>>(
        xnh, w_in, nullptr, zxb, nullptr, nullptr, DPROJ, DIM, DIM, DIM, DPROJ);
    convdt<<<1088, 256, 0, stream>>>(zxb, cw + (size_t)li * CONVDIM * DCONV,
                                     cbias + (size_t)li * CONVDIM,
                                     dtb + li * NH, alog + li * NH, xbc, dtbuf, cabuf);
    cb_kernel<<<NCHUNK, 256, 0, stream>>>(xbc, CBbuf);
    states_k<<<NCHUNK * NH, 256, 0, stream>>>(xbc, dtbuf, cabuf, states);
    scan_k<<<2048, 256, 0, stream>>>(cabuf, states);
    y_fused<<<NCHUNK * NH, 256, 0, stream>>>(xbc, dtbuf, cabuf, CBbuf,
                                             Dvec + li * NH, states, ybuf);
    gate_rms<<<NTOK, 256, 0, stream>>>(ybuf, zxb, nw + (size_t)li * DIN, abh);
    // out_proj: split-K x2; fused reduce(+resid xn) + rms -> xn, xnh
    gemm_p<0><<<dim3(DIM / 128, NTOK / 256, 2), 512, SMEM_BYTES, stream>>>(
        abh, w_out, nullptr, parts, nullptr, nullptr, DIM, DIN / 2, DIN, DIN, DIM);
    reduce_rms<true><<<NTOK, 256, 0, stream>>>(parts, xn, xn, xnh, 2);
    // gated FFN
    gemm_p<2><<<dim3(FFN / 128, NTOK / 256, 1), 512, SMEM_BYTES, stream>>>(
        xnh, w_uv, w_uv + (size_t)FFN * DIM, nullptr, abh, nullptr, FFN, DIM, DIM, DIM, FFN);
    // o_proj: split-K x2; fused reduce + rms (or final f16 convert)
    gemm_p<0><<<dim3(DIM / 128, NTOK / 256, 2), 512, SMEM_BYTES, stream>>>(
        abh, w_o, nullptr, parts, nullptr, nullptr, DIM, FFN / 2, FFN, FFN, DIM);
    if (it < 2 * NLAYER - 1)
      reduce_rms<true><<<NTOK, 256, 0, stream>>>(parts, xn, xn, xnh, 2);
    else
      reduce_rms<false><<<NTOK, 256, 0, stream>>>(parts, xn, nullptr, xh_lm, 2);
  }

  // lm head (single fp16, 256x256 pipelined)
  gemm_p2<<<dim3(VOCAB / 256, NTOK / 256, 1), 512, SMEM2, stream>>>(
      xh_lm, emb_h, (float*)d_out, lmb, VOCAB, DIM, DIM, DIM, VOCAB);
}